// Round 1
// baseline (272.998 us; speedup 1.0000x reference)
//
#include <hip/hip_runtime.h>

// Problem constants (fixed by reference: B=32,D=64,H=32,W=32,K=2048)
#define N_PIX 32768   // B*H*W
#define DIM   64
#define KCODE 2048

// ---------------------------------------------------------------------------
// Kernel A: e_sq[k] = sum_d codebook[k][d]^2
// ---------------------------------------------------------------------------
__global__ void esq_kernel(const float* __restrict__ cb, float* __restrict__ esq) {
    int k = blockIdx.x * blockDim.x + threadIdx.x;
    if (k >= KCODE) return;
    const float4* row = (const float4*)(cb + (size_t)k * DIM);
    float s0 = 0.f, s1 = 0.f, s2 = 0.f, s3 = 0.f;
#pragma unroll
    for (int i = 0; i < DIM / 4; ++i) {
        float4 v = row[i];
        s0 = fmaf(v.x, v.x, s0);
        s1 = fmaf(v.y, v.y, s1);
        s2 = fmaf(v.z, v.z, s2);
        s3 = fmaf(v.w, v.w, s3);
    }
    esq[k] = (s0 + s1) + (s2 + s3);
}

// ---------------------------------------------------------------------------
// Kernel B: per-pixel, per-K-chunk partial argmin of (e_sq - 2*dot(x,e))
//   grid: (N_PIX/64, nchunks), block: 64 (one wave)
//   Thread holds its pixel (64 fp32) in VGPRs; codebook indexed wave-uniformly
//   so the compiler emits scalar loads (constant cache, off the VALU pipe).
// ---------------------------------------------------------------------------
__global__ __launch_bounds__(64)
void dist_kernel(const float* __restrict__ laten, const float* __restrict__ cb,
                 const float* __restrict__ esq,
                 float* __restrict__ pdist, int* __restrict__ pidx,
                 int kper, int nchunks) {
    const int n  = blockIdx.x * 64 + threadIdx.x;   // pixel index (b*1024 + h*32 + w)
    const int b  = n >> 10;
    const int hw = n & 1023;

    // Load x[d] = laten[b][d][h][w]; coalesced across the wave (hw contiguous).
    float x[DIM];
#pragma unroll
    for (int d = 0; d < DIM; ++d)
        x[d] = laten[((size_t)(b * DIM + d) << 10) + hw];

    const int c0 = blockIdx.y * kper;
    float best  = 3.4e38f;
    int   bestI = c0;

    for (int c = c0; c < c0 + kper; ++c) {
        const float4* row = (const float4*)(cb + (size_t)c * DIM);  // uniform -> s_load
        float a0 = 0.f, a1 = 0.f, a2 = 0.f, a3 = 0.f;
#pragma unroll
        for (int i = 0; i < DIM / 4; ++i) {
            float4 v = row[i];
            a0 = fmaf(v.x, x[4 * i + 0], a0);
            a1 = fmaf(v.y, x[4 * i + 1], a1);
            a2 = fmaf(v.z, x[4 * i + 2], a2);
            a3 = fmaf(v.w, x[4 * i + 3], a3);
        }
        float dot  = (a0 + a1) + (a2 + a3);
        float dist = esq[c] - 2.0f * dot;           // x_sq and /D don't affect argmin
        if (dist < best) { best = dist; bestI = c; } // strict < keeps lowest idx on ties
    }
    pdist[(size_t)n * nchunks + blockIdx.y] = best;
    pidx [(size_t)n * nchunks + blockIdx.y] = bestI;
}

// ---------------------------------------------------------------------------
// Kernel C1: merge chunk partials -> final idx; out0[n] = (float)idx
// ---------------------------------------------------------------------------
__global__ void merge_kernel(const float* __restrict__ pdist, const int* __restrict__ pidx,
                             float* __restrict__ out0, int* __restrict__ idxf,
                             int nchunks) {
    int n = blockIdx.x * blockDim.x + threadIdx.x;
    if (n >= N_PIX) return;
    float best = pdist[(size_t)n * nchunks];
    int   bi   = pidx [(size_t)n * nchunks];
    for (int j = 1; j < nchunks; ++j) {
        float dj = pdist[(size_t)n * nchunks + j];
        int   ij = pidx [(size_t)n * nchunks + j];
        if (dj < best) { best = dj; bi = ij; }      // chunks scan increasing c: ties keep low idx
    }
    out0[n] = (float)bi;
    idxf[n] = bi;
}

// ---------------------------------------------------------------------------
// Kernel C2: quant_laten[b][d][h][w] = codebook[idx[b][h][w]][d]
//   One thread per output element; writes fully coalesced.
// ---------------------------------------------------------------------------
__global__ void gather_kernel(const float* __restrict__ cb, const int* __restrict__ idxf,
                              float* __restrict__ out1) {
    int t  = blockIdx.x * 256 + threadIdx.x;        // t = b*65536 + d*1024 + hw
    int b  = t >> 16;
    int d  = (t >> 10) & (DIM - 1);
    int hw = t & 1023;
    int idx = idxf[(b << 10) + hw];
    out1[t] = cb[(size_t)idx * DIM + d];
}

// ---------------------------------------------------------------------------
extern "C" void kernel_launch(void* const* d_in, const int* in_sizes, int n_in,
                              void* d_out, int out_size, void* d_ws, size_t ws_size,
                              hipStream_t stream) {
    const float* laten = (const float*)d_in[0];   // (32,64,32,32) fp32
    const float* cb    = (const float*)d_in[1];   // (2048,64) fp32

    float* out0 = (float*)d_out;                  // indices as float, N_PIX elems
    float* out1 = (float*)d_out + N_PIX;          // quant_laten, 2M elems

    // Pick chunk count that fits the workspace:
    // ws floats needed = 2048 (esq) + N*nc (pdist) + N*nc (pidx) + N (idxf)
    int nchunks = 8;
    while (nchunks > 1 &&
           (size_t)(2048 + (size_t)N_PIX * nchunks * 2 + N_PIX) * 4 > ws_size)
        nchunks >>= 1;
    const int kper = KCODE / nchunks;

    float* esq   = (float*)d_ws;                          // 2048
    float* pdist = esq + 2048;                            // N*nchunks
    int*   pidx  = (int*)(pdist + (size_t)N_PIX * nchunks);
    int*   idxf  = (int*)((float*)pidx + (size_t)N_PIX * nchunks);

    esq_kernel<<<KCODE / 256, 256, 0, stream>>>(cb, esq);

    dim3 gridB(N_PIX / 64, nchunks);
    dist_kernel<<<gridB, 64, 0, stream>>>(laten, cb, esq, pdist, pidx, kper, nchunks);

    merge_kernel<<<N_PIX / 256, 256, 0, stream>>>(pdist, pidx, out0, idxf, nchunks);

    gather_kernel<<<(N_PIX * DIM) / 256, 256, 0, stream>>>(cb, idxf, out1);
}